// Round 5
// baseline (174.452 us; speedup 1.0000x reference)
//
#include <hip/hip_runtime.h>
#include <hip/hip_bf16.h>
#include <math.h>

// Problem constants (B=1)
#define HH 16
#define WW 16
#define DD 16
#define LL 4096          // H*W*Dd
#define CC 48            // d_model
#define DIN 48           // d_inner
#define NN 16            // d_state
#define RR 3             // dt_rank
#define KK 8             // scan directions
#define KD 384           // K*DIN
#define SNCH 64          // chunks along L (fused scan)
#define SCHL 64          // chunk length
#define PCH 68           // padded LDS chunk stride (floats): banks (4c+i)%32, 16B-aligned

// ---------------- Kernel 1: in_proj  xz[l,e] = sum_c x[l,c]*W[e,c] ----------
__global__ __launch_bounds__(256) void k_inproj(const float* __restrict__ x,
                                                const float* __restrict__ W,
                                                float* __restrict__ xm,
                                                float* __restrict__ z) {
    int tid = blockIdx.x * 256 + threadIdx.x;          // l*96 + e
    if (tid >= LL * 96) return;
    int e = tid % 96, l = tid / 96;
    const float4* xr = (const float4*)(x + l * CC);
    const float4* wr = (const float4*)(W + e * CC);
    float acc = 0.f;
#pragma unroll
    for (int c4 = 0; c4 < CC / 4; ++c4) {
        float4 a = xr[c4], b = wr[c4];
        acc += a.x * b.x + a.y * b.y + a.z * b.z + a.w * b.w;
    }
    if (e < DIN) xm[e * LL + l] = acc;
    else         z[l * DIN + (e - DIN)] = acc;
}

// ---- Kernel 2: depthwise 3x3x3 conv + bias + SiLU + 8-way scatter to xs ----
__global__ __launch_bounds__(256) void k_convscat(const float* __restrict__ xm,
                                                  const float* __restrict__ cw,
                                                  const float* __restrict__ cb,
                                                  float* __restrict__ xs) {
    int tid = blockIdx.x * 256 + threadIdx.x;          // d*LL + s
    if (tid >= DIN * LL) return;
    int s = tid & (LL - 1), d = tid >> 12;
    int dd = s & 15, w = (s >> 4) & 15, h = s >> 8;
    const float* wp = cw + d * 27;
    const float* xp = xm + d * LL;
    float acc = 0.f;
#pragma unroll
    for (int i = -1; i <= 1; ++i) {
        int hh = h + i; if (hh < 0 || hh > 15) continue;
#pragma unroll
        for (int j = -1; j <= 1; ++j) {
            int ww2 = w + j; if (ww2 < 0 || ww2 > 15) continue;
#pragma unroll
            for (int q = -1; q <= 1; ++q) {
                int dd2 = dd + q; if (dd2 < 0 || dd2 > 15) continue;
                acc += wp[(i + 1) * 9 + (j + 1) * 3 + (q + 1)]
                     * xp[hh * 256 + ww2 * 16 + dd2];
            }
        }
    }
    acc += cb[d];
    float v = acc / (1.f + __expf(-acc));              // SiLU
    int p0 = s;
    int p1 = w * 256 + h * 16 + dd;                    // swap h,w
    int p2 = dd * 256 + w * 16 + h;                    // swap h,dd
    int p3 = h * 256 + dd * 16 + w;                    // swap w,dd
    xs[(size_t)(0 * DIN + d) * LL + p0] = v;
    xs[(size_t)(1 * DIN + d) * LL + p1] = v;
    xs[(size_t)(2 * DIN + d) * LL + p2] = v;
    xs[(size_t)(3 * DIN + d) * LL + p3] = v;
    xs[(size_t)(4 * DIN + d) * LL + (LL - 1 - p0)] = v;
    xs[(size_t)(5 * DIN + d) * LL + (LL - 1 - p1)] = v;
    xs[(size_t)(6 * DIN + d) * LL + (LL - 1 - p2)] = v;
    xs[(size_t)(7 * DIN + d) * LL + (LL - 1 - p3)] = v;
}

// ---- Kernel 3: x_proj + dt_proj fused. Block per (k, 64-l tile). ----------
// xs tile staged in LDS once (was 35x re-read through L1).
__global__ __launch_bounds__(256) void k_xproj2(const float* __restrict__ xs,
                                                const float* __restrict__ xpw,
                                                const float* __restrict__ dtw,
                                                const float* __restrict__ dtb,
                                                float* __restrict__ BC,
                                                float* __restrict__ dsp) {
    int k = blockIdx.x >> 6;
    int l0 = (blockIdx.x & 63) * 64;
    int tid = threadIdx.x;
    __shared__ float xt[48 * 68];                      // xs tile [d][64+4pad]
    __shared__ float xd[35 * 65];                      // x_dbl tile, pad 65
    __shared__ float wl[35 * 49];                      // weights, pad 49
    for (int i = tid; i < 35 * 48; i += 256)
        wl[(i / 48) * 49 + (i % 48)] = xpw[k * 35 * 48 + i];
    // stage xs tile: 48 d x 16 float4
#pragma unroll
    for (int it = 0; it < 3; ++it) {
        int idx = it * 256 + tid;                      // 0..767
        int d = idx >> 4, w = idx & 15;
        float4 v = ((const float4*)(xs + (size_t)(k * DIN + d) * LL + l0))[w];
        ((float4*)(xt + d * 68))[w] = v;
    }
    __syncthreads();
    // Phase A: x_dbl[c][l] for c=0..34, l tile of 64 (as 16 float4 groups)
#pragma unroll
    for (int it = 0; it < 3; ++it) {
        int item = it * 256 + tid;
        if (item < 560) {
            int c = item % 35, l4 = item / 35;
            const float* wr = wl + c * 49;
            float4 acc = {0.f, 0.f, 0.f, 0.f};
#pragma unroll
            for (int d2 = 0; d2 < 48; ++d2) {
                float4 v = ((const float4*)(xt + d2 * 68))[l4];
                float w = wr[d2];
                acc.x += v.x * w; acc.y += v.y * w; acc.z += v.z * w; acc.w += v.w * w;
            }
            float* o = xd + c * 65 + l4 * 4;
            o[0] = acc.x; o[1] = acc.y; o[2] = acc.z; o[3] = acc.w;
        }
    }
    __syncthreads();
    // Phase B: write B/C rows (c=3..34) coalesced, stride-32 layout
#pragma unroll
    for (int it = 0; it < 8; ++it) {
        int idx = it * 256 + tid;                      // 2048 = 64 l * 32 c
        int l = idx >> 5, c = idx & 31;
        BC[((size_t)k * LL + l0 + l) * 32 + c] = xd[(c + 3) * 65 + l];
    }
    // Phase C: delta = softplus(dts @ dtw + bias)
#pragma unroll
    for (int it = 0; it < 12; ++it) {
        int idx = it * 256 + tid;                      // 3072 = 48 d * 64 l
        int d2 = idx >> 6, l = idx & 63;
        int gd = k * DIN + d2;
        float v = xd[l] * dtw[gd * 3] + xd[65 + l] * dtw[gd * 3 + 1]
                + xd[130 + l] * dtw[gd * 3 + 2] + dtb[gd];
        dsp[(size_t)gd * LL + l0 + l] = (v > 20.f) ? v : log1pf(__expf(v));
    }
}

// ---- Kernel 4: fused 3-phase selective scan. Block per gid=(k,d). ----------
// 1024 threads = 64 chunks x 16 states. Padded LDS (conflict-free), y
// accumulated in LDS and stored coalesced to y4[gid][l].
__global__ __launch_bounds__(1024) void k_scanf(const float* __restrict__ xs,
                                                const float* __restrict__ dsp,
                                                const float* __restrict__ BC,
                                                const float* __restrict__ A_logs,
                                                const float* __restrict__ Ds,
                                                float* __restrict__ y4) {
    int gid = blockIdx.x;                              // k*DIN + d
    int k = gid / DIN;
    int t = threadIdx.x;
    int n = t & 15, c = t >> 4;                        // c: 0..63
    __shared__ float u_lds[SNCH * PCH];                // 4352 floats
    __shared__ float d_lds[SNCH * PCH];
    __shared__ float y_lds[SNCH * PCH];
    __shared__ float pa_lds[SNCH * 16];
    __shared__ float hf_lds[SNCH * 16];
    __shared__ float h0_lds[SNCH * 16];                // total 63 KB
    {
        // one float4 per thread: chunk c2 = t>>4, word w = t&15
        int c2 = t >> 4, w = t & 15;
        float4 uv = ((const float4*)(xs + (size_t)gid * LL))[t];
        float4 dv = ((const float4*)(dsp + (size_t)gid * LL))[t];
        ((float4*)u_lds)[c2 * (PCH / 4) + w] = uv;
        ((float4*)d_lds)[c2 * (PCH / 4) + w] = dv;
    }
    __syncthreads();
    float A = -__expf(A_logs[gid * NN + n]);
    const float* bp = BC + ((size_t)k * LL + c * SCHL) * 32 + n;
    const float* cp = bp + 16;
    int base = c * PCH;
    // Phase 1: local chunk scan
    float h = 0.f, pa = 1.f;
#pragma unroll 4
    for (int i = 0; i < SCHL; ++i) {
        float delta = d_lds[base + i];
        float u = u_lds[base + i];
        float Bv = bp[(size_t)i * 32];
        float dA = __expf(delta * A);
        h = h * dA + delta * u * Bv;
        pa *= dA;
    }
    pa_lds[t] = pa;
    hf_lds[t] = h;
    __syncthreads();
    // Phase 2: serial combine over 64 chunks (16 lanes, one per state)
    if (t < 16) {
        float hh = 0.f;
#pragma unroll 8
        for (int cc = 0; cc < SNCH; ++cc) {
            int idx = cc * 16 + t;
            h0_lds[idx] = hh;
            hh = hh * pa_lds[idx] + hf_lds[idx];
        }
    }
    __syncthreads();
    // Phase 3: re-scan seeded with h0, reduce over n, y into LDS
    h = h0_lds[t];
    float Dv = Ds[gid];
#pragma unroll 4
    for (int i = 0; i < SCHL; ++i) {
        float delta = d_lds[base + i];
        float u = u_lds[base + i];
        float Bv = bp[(size_t)i * 32];
        float Cv = cp[(size_t)i * 32];
        float dA = __expf(delta * A);
        h = h * dA + delta * u * Bv;
        float p = h * Cv;
        p += __shfl_xor(p, 1, 64);
        p += __shfl_xor(p, 2, 64);
        p += __shfl_xor(p, 4, 64);
        p += __shfl_xor(p, 8, 64);
        if (n == 0) y_lds[base + i] = p + Dv * u;
    }
    __syncthreads();
    // coalesced store: y4[gid][l]
    {
        int c2 = t >> 4, w = t & 15;
        float4 v = ((const float4*)y_lds)[c2 * (PCH / 4) + w];
        ((float4*)(y4 + (size_t)gid * LL))[t] = v;
    }
}

// ---- Kernel 5: transpose y4[k][d][l] -> y2[s][k][d] (de-permute) -----------
// Block per (k, 128-l tile): coalesced reads, 192B-contiguous writes.
__global__ __launch_bounds__(256) void k_trans(const float* __restrict__ y4,
                                               float* __restrict__ y2) {
    int k = blockIdx.x >> 5;
    int l0 = (blockIdx.x & 31) * 128;
    int tid = threadIdx.x;
    __shared__ float ty[48 * 129];                     // [d][128+1 pad]
    // load 48 d x 128 l, scalar coalesced (consecutive lanes = consecutive l)
#pragma unroll
    for (int it = 0; it < 24; ++it) {
        int idx = it * 256 + tid;                      // 0..6143
        int l = idx & 127, d = idx >> 7;
        ty[d * 129 + l] = y4[(size_t)(k * DIN + d) * LL + l0 + l];
    }
    __syncthreads();
    // write: per l, 48 contiguous floats at y2[s*KD + k*48]
#pragma unroll
    for (int it = 0; it < 6; ++it) {
        int idx = it * 256 + tid;                      // 0..1535 = 128 l * 12 f4
        int l = idx / 12, g = idx % 12;
        int lg = l0 + l;
        int ll = (k & 4) ? (LL - 1 - lg) : lg;
        int a = ll >> 8, b2 = (ll >> 4) & 15, c2 = ll & 15;
        int s;
        switch (k & 3) {
            case 0: s = ll;                        break;
            case 1: s = b2 * 256 + a * 16 + c2;    break;
            case 2: s = c2 * 256 + b2 * 16 + a;    break;
            default: s = a * 256 + c2 * 16 + b2;   break;
        }
        float4 v;
        v.x = ty[(g * 4 + 0) * 129 + l];
        v.y = ty[(g * 4 + 1) * 129 + l];
        v.z = ty[(g * 4 + 2) * 129 + l];
        v.w = ty[(g * 4 + 3) * 129 + l];
        ((float4*)(y2 + (size_t)s * KD))[k * 12 + g] = v;
    }
}

// ---- Kernel 6: sum dirs + LayerNorm + gate + out_proj. Wave per s. ---------
__global__ __launch_bounds__(256) void k_final2(const float* __restrict__ y2,
                                                const float* __restrict__ z,
                                                const float* __restrict__ nw,
                                                const float* __restrict__ nb,
                                                const float* __restrict__ opw,
                                                float* __restrict__ out) {
    int wv = threadIdx.x >> 6, lane = threadIdx.x & 63;
    int s = blockIdx.x * 4 + wv;
    __shared__ float g[4][DIN];
    float val = 0.f;
    if (lane < DIN) {
        const float* yp = y2 + (size_t)s * (KK * DIN) + lane;
#pragma unroll
        for (int k = 0; k < KK; ++k) val += yp[k * DIN];
    }
    float m = val;
#pragma unroll
    for (int o = 32; o >= 1; o >>= 1) m += __shfl_xor(m, o, 64);
    m *= (1.f / 48.f);
    float dv = (lane < DIN) ? (val - m) : 0.f;
    float v2 = dv * dv;
#pragma unroll
    for (int o = 32; o >= 1; o >>= 1) v2 += __shfl_xor(v2, o, 64);
    v2 *= (1.f / 48.f);
    float inv = rsqrtf(v2 + 1e-5f);
    if (lane < DIN) {
        float yn = dv * inv * nw[lane] + nb[lane];
        float zz = z[s * DIN + lane];
        g[wv][lane] = yn * (zz / (1.f + __expf(-zz)));
    }
    __syncthreads();
    if (lane < DIN) {
        const float* wr = opw + lane * DIN;            // out_proj_w[c, e]
        float acc = 0.f;
#pragma unroll
        for (int e = 0; e < DIN; ++e) acc += g[wv][e] * wr[e];
        out[s * CC + lane] = acc;
    }
}

extern "C" void kernel_launch(void* const* d_in, const int* in_sizes, int n_in,
                              void* d_out, int out_size, void* d_ws, size_t ws_size,
                              hipStream_t stream) {
    const float* x      = (const float*)d_in[0];
    const float* ipw    = (const float*)d_in[1];
    const float* cw     = (const float*)d_in[2];
    const float* cb     = (const float*)d_in[3];
    const float* xpw    = (const float*)d_in[4];
    const float* dtw    = (const float*)d_in[5];
    const float* dtb    = (const float*)d_in[6];
    const float* A_logs = (const float*)d_in[7];
    const float* Ds     = (const float*)d_in[8];
    const float* nw     = (const float*)d_in[9];
    const float* nb     = (const float*)d_in[10];
    const float* opw    = (const float*)d_in[11];
    float* out = (float*)d_out;

    float* ws  = (float*)d_ws;
    float* xm  = ws;                                   // DIN*LL
    float* z   = xm + DIN * LL;                        // LL*DIN
    float* xs  = z + LL * DIN;                         // KD*LL
    float* BC  = xs + (size_t)KD * LL;                 // KK*LL*32
    float* dsp = BC + (size_t)KK * LL * 32;            // KD*LL
    float* y4  = dsp + (size_t)KD * LL;                // KD*LL (scan order)
    float* y2  = y4 + (size_t)KD * LL;                 // LL*KK*DIN (s-major)

    k_inproj<<<(LL * 96 + 255) / 256, 256, 0, stream>>>(x, ipw, xm, z);
    k_convscat<<<(DIN * LL + 255) / 256, 256, 0, stream>>>(xm, cw, cb, xs);
    k_xproj2<<<KK * 64, 256, 0, stream>>>(xs, xpw, dtw, dtb, BC, dsp);
    k_scanf<<<KD, 1024, 0, stream>>>(xs, dsp, BC, A_logs, Ds, y4);
    k_trans<<<KK * 32, 256, 0, stream>>>(y4, y2);
    k_final2<<<LL / 4, 256, 0, stream>>>(y2, z, nw, nb, opw, out);
}

// Round 6
// 167.922 us; speedup vs baseline: 1.0389x; 1.0389x over previous
//
#include <hip/hip_runtime.h>
#include <hip/hip_bf16.h>
#include <math.h>

// Problem constants (B=1)
#define HH 16
#define WW 16
#define DD 16
#define LL 4096          // H*W*Dd
#define CC 48            // d_model
#define DIN 48           // d_inner
#define NN 16            // d_state
#define RR 3             // dt_rank
#define KK 8             // scan directions
#define KD 384           // K*DIN
#define NCH 64           // chunks along L
#define CHL 64           // chunk length

// ---------------- Kernel 1: in_proj  xz[l,e] = sum_c x[l,c]*W[e,c] ----------
__global__ __launch_bounds__(256) void k_inproj(const float* __restrict__ x,
                                                const float* __restrict__ W,
                                                float* __restrict__ xm,
                                                float* __restrict__ z) {
    int tid = blockIdx.x * 256 + threadIdx.x;          // l*96 + e
    if (tid >= LL * 96) return;
    int e = tid % 96, l = tid / 96;
    const float4* xr = (const float4*)(x + l * CC);
    const float4* wr = (const float4*)(W + e * CC);
    float acc = 0.f;
#pragma unroll
    for (int c4 = 0; c4 < CC / 4; ++c4) {
        float4 a = xr[c4], b = wr[c4];
        acc += a.x * b.x + a.y * b.y + a.z * b.z + a.w * b.w;
    }
    if (e < DIN) xm[e * LL + l] = acc;
    else         z[l * DIN + (e - DIN)] = acc;
}

// ---- Kernel 2: depthwise 3x3x3 conv + bias + SiLU + 8-way scatter to xs ----
__global__ __launch_bounds__(256) void k_convscat(const float* __restrict__ xm,
                                                  const float* __restrict__ cw,
                                                  const float* __restrict__ cb,
                                                  float* __restrict__ xs) {
    int tid = blockIdx.x * 256 + threadIdx.x;          // d*LL + s
    if (tid >= DIN * LL) return;
    int s = tid & (LL - 1), d = tid >> 12;
    int dd = s & 15, w = (s >> 4) & 15, h = s >> 8;
    const float* wp = cw + d * 27;
    const float* xp = xm + d * LL;
    float acc = 0.f;
#pragma unroll
    for (int i = -1; i <= 1; ++i) {
        int hh = h + i; if (hh < 0 || hh > 15) continue;
#pragma unroll
        for (int j = -1; j <= 1; ++j) {
            int ww2 = w + j; if (ww2 < 0 || ww2 > 15) continue;
#pragma unroll
            for (int q = -1; q <= 1; ++q) {
                int dd2 = dd + q; if (dd2 < 0 || dd2 > 15) continue;
                acc += wp[(i + 1) * 9 + (j + 1) * 3 + (q + 1)]
                     * xp[hh * 256 + ww2 * 16 + dd2];
            }
        }
    }
    acc += cb[d];
    float v = acc / (1.f + __expf(-acc));              // SiLU
    int p0 = s;
    int p1 = w * 256 + h * 16 + dd;                    // swap h,w
    int p2 = dd * 256 + w * 16 + h;                    // swap h,dd
    int p3 = h * 256 + dd * 16 + w;                    // swap w,dd
    xs[(size_t)(0 * DIN + d) * LL + p0] = v;
    xs[(size_t)(1 * DIN + d) * LL + p1] = v;
    xs[(size_t)(2 * DIN + d) * LL + p2] = v;
    xs[(size_t)(3 * DIN + d) * LL + p3] = v;
    xs[(size_t)(4 * DIN + d) * LL + (LL - 1 - p0)] = v;
    xs[(size_t)(5 * DIN + d) * LL + (LL - 1 - p1)] = v;
    xs[(size_t)(6 * DIN + d) * LL + (LL - 1 - p2)] = v;
    xs[(size_t)(7 * DIN + d) * LL + (LL - 1 - p3)] = v;
}

// ---- Kernel 3: x_proj + dt_proj + scan PHASE 1, fused. Block (k, chunk). ---
// 768 threads = 48 d x 16 n. x_dbl tile lives in LDS; phase-1 scan reads
// B and delta straight from LDS (BC shared across all 48 d -> read once).
// Emits BC + dsp to global (for phase 3) and pa/hf chunk summaries.
__global__ __launch_bounds__(768) void k_xscan1(const float* __restrict__ xs,
                                                const float* __restrict__ xpw,
                                                const float* __restrict__ dtw,
                                                const float* __restrict__ dtb,
                                                const float* __restrict__ A_logs,
                                                float* __restrict__ BC,
                                                float* __restrict__ dsp,
                                                float* __restrict__ pa_g,
                                                float* __restrict__ hf_g) {
    int k = blockIdx.x >> 6;
    int c = blockIdx.x & (NCH - 1);
    int l0 = c * CHL;
    int tid = threadIdx.x;
    __shared__ float xt[48 * 68];                      // u tile [d][64], pad 68
    __shared__ float xd[35 * 65];                      // x_dbl [c][64], pad 65
    __shared__ float wl[35 * 49];                      // x_proj weights
    __shared__ float dt[48 * 68];                      // delta tile
    for (int i = tid; i < 35 * 48; i += 768)
        wl[(i / 48) * 49 + (i % 48)] = xpw[k * 35 * 48 + i];
    {   // stage u tile: 48 d x 16 float4, coalesced
        int d = tid >> 4, w = tid & 15;
        float4 v = ((const float4*)(xs + (size_t)(k * DIN + d) * LL + l0))[w];
        ((float4*)(xt + d * 68))[w] = v;
    }
    __syncthreads();
    // x_dbl: 35 c x 16 l4 = 560 items, one round
    if (tid < 560) {
        int cc = tid % 35, l4 = tid / 35;
        const float* wr = wl + cc * 49;
        float4 acc = {0.f, 0.f, 0.f, 0.f};
#pragma unroll
        for (int d2 = 0; d2 < 48; ++d2) {
            float4 v = ((const float4*)(xt + d2 * 68))[l4];
            float w = wr[d2];
            acc.x += v.x * w; acc.y += v.y * w; acc.z += v.z * w; acc.w += v.w * w;
        }
        float* o = xd + cc * 65 + l4 * 4;
        o[0] = acc.x; o[1] = acc.y; o[2] = acc.z; o[3] = acc.w;
    }
    __syncthreads();
    // write BC rows (float4 over the 32 B/C cols), coalesced-ish
    if (tid < 512) {
        int l = tid >> 3, q = tid & 7;
        float4 v;
#pragma unroll
        for (int j = 0; j < 4; ++j) (&v.x)[j] = xd[(3 + q * 4 + j) * 65 + l];
        ((float4*)(BC + ((size_t)(k * LL + l0 + l)) * 32))[q] = v;
    }
    // delta = softplus(dts @ dtw + bias): 48 d x 64 l = 3072, 4 rounds
#pragma unroll
    for (int r = 0; r < 4; ++r) {
        int idx = r * 768 + tid;
        int d2 = idx >> 6, l = idx & 63;
        int gd = k * DIN + d2;
        float v = xd[l] * dtw[gd * 3] + xd[65 + l] * dtw[gd * 3 + 1]
                + xd[130 + l] * dtw[gd * 3 + 2] + dtb[gd];
        float sp = (v > 20.f) ? v : log1pf(__expf(v));
        dt[d2 * 68 + l] = sp;
        dsp[(size_t)gd * LL + l0 + l] = sp;
    }
    __syncthreads();
    // scan phase 1: local chunk scan, h starts at 0
    int d = tid >> 4, n = tid & 15;
    int gid = k * DIN + d;
    float A = -__expf(A_logs[gid * NN + n]);
    float h = 0.f, pa = 1.f;
#pragma unroll 4
    for (int i = 0; i < CHL; ++i) {
        float delta = dt[d * 68 + i];
        float u = xt[d * 68 + i];
        float Bv = xd[(3 + n) * 65 + i];
        float dA = __expf(delta * A);
        h = h * dA + delta * u * Bv;
        pa *= dA;
    }
    size_t si = (size_t)gid * (NCH * 16) + c * 16 + n;
    pa_g[si] = pa;
    hf_g[si] = h;
}

// ---- Kernel 4: scan PHASE 2 — serial combine over 64 chunk summaries. ------
__global__ __launch_bounds__(256) void k_scan2(const float* __restrict__ pa_g,
                                               const float* __restrict__ hf_g,
                                               float* __restrict__ h0_g) {
    int t = blockIdx.x * 256 + threadIdx.x;            // gid*16 + n
    if (t >= KD * NN) return;
    int n = t & 15;
    int gid = t >> 4;
    size_t base = (size_t)gid * (NCH * 16) + n;
    float h = 0.f;
#pragma unroll 4
    for (int c = 0; c < NCH; ++c) {
        size_t idx = base + (size_t)c * 16;
        h0_g[idx] = h;
        h = h * pa_g[idx] + hf_g[idx];
    }
}

// ---- Kernel 5: scan PHASE 3 — re-scan seeded, de-permuted y2 store. --------
// Block (k, chunk), 768 threads. u/delta/BC read through L1 (32KB working
// set). y transposed in LDS, stored as y2[s][k*48..+47] (192B contiguous).
__global__ __launch_bounds__(768) void k_scan3(const float* __restrict__ xs,
                                               const float* __restrict__ dsp,
                                               const float* __restrict__ BC,
                                               const float* __restrict__ A_logs,
                                               const float* __restrict__ Ds,
                                               const float* __restrict__ h0_g,
                                               float* __restrict__ y2) {
    int k = blockIdx.x >> 6;
    int c = blockIdx.x & (NCH - 1);
    int l0 = c * CHL;
    int tid = threadIdx.x;
    int d = tid >> 4, n = tid & 15;
    int gid = k * DIN + d;
    __shared__ float y_t[48 * 68];
    float A = -__expf(A_logs[gid * NN + n]);
    float Dv = Ds[gid];
    float h = h0_g[(size_t)gid * (NCH * 16) + c * 16 + n];
    const float* up = xs + (size_t)gid * LL + l0;
    const float* dp = dsp + (size_t)gid * LL + l0;
    const float* bp = BC + ((size_t)(k * LL + l0)) * 32 + n;
    const float* cp = bp + 16;
#pragma unroll 4
    for (int i = 0; i < CHL; ++i) {
        float delta = dp[i];
        float u = up[i];
        float Bv = bp[(size_t)i * 32];
        float Cv = cp[(size_t)i * 32];
        float dA = __expf(delta * A);
        h = h * dA + delta * u * Bv;
        float p = h * Cv;
        p += __shfl_xor(p, 1, 64);
        p += __shfl_xor(p, 2, 64);
        p += __shfl_xor(p, 4, 64);
        p += __shfl_xor(p, 8, 64);
        if (n == 0) y_t[d * 68 + i] = p + Dv * u;
    }
    __syncthreads();
    // transpose-store: thread (g = tid>>6 in 0..11, l = tid&63)
    {
        int g = tid >> 6, l = tid & 63;
        int lg = l0 + l;
        int ll = (k & 4) ? (LL - 1 - lg) : lg;
        int a = ll >> 8, b2 = (ll >> 4) & 15, c2 = ll & 15;
        int s;
        switch (k & 3) {
            case 0: s = ll;                        break;
            case 1: s = b2 * 256 + a * 16 + c2;    break;
            case 2: s = c2 * 256 + b2 * 16 + a;    break;
            default: s = a * 256 + c2 * 16 + b2;   break;
        }
        float4 v;
#pragma unroll
        for (int j = 0; j < 4; ++j) (&v.x)[j] = y_t[(g * 4 + j) * 68 + l];
        ((float4*)(y2 + (size_t)s * KD + k * DIN))[g] = v;
    }
}

// ---- Kernel 6: sum dirs + LayerNorm + gate + out_proj. Wave per s. ---------
__global__ __launch_bounds__(256) void k_final2(const float* __restrict__ y2,
                                                const float* __restrict__ z,
                                                const float* __restrict__ nw,
                                                const float* __restrict__ nb,
                                                const float* __restrict__ opw,
                                                float* __restrict__ out) {
    int wv = threadIdx.x >> 6, lane = threadIdx.x & 63;
    int s = blockIdx.x * 4 + wv;
    __shared__ float g[4][DIN];
    float val = 0.f;
    if (lane < DIN) {
        const float* yp = y2 + (size_t)s * KD + lane;
#pragma unroll
        for (int k = 0; k < KK; ++k) val += yp[k * DIN];
    }
    float m = val;
#pragma unroll
    for (int o = 32; o >= 1; o >>= 1) m += __shfl_xor(m, o, 64);
    m *= (1.f / 48.f);
    float dv = (lane < DIN) ? (val - m) : 0.f;
    float v2 = dv * dv;
#pragma unroll
    for (int o = 32; o >= 1; o >>= 1) v2 += __shfl_xor(v2, o, 64);
    v2 *= (1.f / 48.f);
    float inv = rsqrtf(v2 + 1e-5f);
    if (lane < DIN) {
        float yn = dv * inv * nw[lane] + nb[lane];
        float zz = z[s * DIN + lane];
        g[wv][lane] = yn * (zz / (1.f + __expf(-zz)));
    }
    __syncthreads();
    if (lane < DIN) {
        const float* wr = opw + lane * DIN;            // out_proj_w[c, e]
        float acc = 0.f;
#pragma unroll
        for (int e = 0; e < DIN; ++e) acc += g[wv][e] * wr[e];
        out[s * CC + lane] = acc;
    }
}

extern "C" void kernel_launch(void* const* d_in, const int* in_sizes, int n_in,
                              void* d_out, int out_size, void* d_ws, size_t ws_size,
                              hipStream_t stream) {
    const float* x      = (const float*)d_in[0];
    const float* ipw    = (const float*)d_in[1];
    const float* cw     = (const float*)d_in[2];
    const float* cb     = (const float*)d_in[3];
    const float* xpw    = (const float*)d_in[4];
    const float* dtw    = (const float*)d_in[5];
    const float* dtb    = (const float*)d_in[6];
    const float* A_logs = (const float*)d_in[7];
    const float* Ds     = (const float*)d_in[8];
    const float* nw     = (const float*)d_in[9];
    const float* nb     = (const float*)d_in[10];
    const float* opw    = (const float*)d_in[11];
    float* out = (float*)d_out;

    float* ws   = (float*)d_ws;
    float* xm   = ws;                                  // DIN*LL
    float* z    = xm + DIN * LL;                       // LL*DIN
    float* xs   = z + LL * DIN;                        // KD*LL
    float* BC   = xs + (size_t)KD * LL;                // KK*LL*32
    float* dsp  = BC + (size_t)KK * LL * 32;           // KD*LL
    float* y2   = dsp + (size_t)KD * LL;               // LL*KD (s-major)
    float* pa_g = y2 + (size_t)LL * KD;                // KD*NCH*16
    float* hf_g = pa_g + (size_t)KD * NCH * 16;
    float* h0_g = hf_g + (size_t)KD * NCH * 16;

    k_inproj<<<(LL * 96 + 255) / 256, 256, 0, stream>>>(x, ipw, xm, z);
    k_convscat<<<(DIN * LL + 255) / 256, 256, 0, stream>>>(xm, cw, cb, xs);
    k_xscan1<<<KK * NCH, 768, 0, stream>>>(xs, xpw, dtw, dtb, A_logs,
                                           BC, dsp, pa_g, hf_g);
    k_scan2<<<(KD * NN + 255) / 256, 256, 0, stream>>>(pa_g, hf_g, h0_g);
    k_scan3<<<KK * NCH, 768, 0, stream>>>(xs, dsp, BC, A_logs, Ds, h0_g, y2);
    k_final2<<<LL / 4, 256, 0, stream>>>(y2, z, nw, nb, opw, out);
}

// Round 7
// 155.018 us; speedup vs baseline: 1.1254x; 1.0832x over previous
//
#include <hip/hip_runtime.h>
#include <hip/hip_bf16.h>
#include <math.h>

// Problem constants (B=1)
#define HH 16
#define WW 16
#define DD 16
#define LL 4096          // H*W*Dd
#define CC 48            // d_model
#define DIN 48           // d_inner
#define NN 16            // d_state
#define RR 3             // dt_rank
#define KK 8             // scan directions
#define KD 384           // K*DIN
#define NCH 64           // chunks along L
#define CHL 64           // chunk length

// DPP-based 16-lane (within-row) sum: xor1, xor2 via quad_perm; then
// row_ror:4 + row_ror:8 complete the 16-lane reduction. Pure VALU, no LDS.
__device__ __forceinline__ float dpp_add(float x, const int ctrl_tag) {
    int xi = __float_as_int(x);
    int yi;
    switch (ctrl_tag) {
        case 0: yi = __builtin_amdgcn_update_dpp(0, xi, 0xB1, 0xF, 0xF, true); break; // quad_perm [1,0,3,2]
        case 1: yi = __builtin_amdgcn_update_dpp(0, xi, 0x4E, 0xF, 0xF, true); break; // quad_perm [2,3,0,1]
        case 2: yi = __builtin_amdgcn_update_dpp(0, xi, 0x124, 0xF, 0xF, true); break; // row_ror:4
        default: yi = __builtin_amdgcn_update_dpp(0, xi, 0x128, 0xF, 0xF, true); break; // row_ror:8
    }
    return x + __int_as_float(yi);
}
__device__ __forceinline__ float row16_sum(float p) {
    p = dpp_add(p, 0);
    p = dpp_add(p, 1);
    p = dpp_add(p, 2);
    p = dpp_add(p, 3);
    return p;
}

// ---------------- Kernel 1: in_proj  xz[l,e] = sum_c x[l,c]*W[e,c] ----------
__global__ __launch_bounds__(256) void k_inproj(const float* __restrict__ x,
                                                const float* __restrict__ W,
                                                float* __restrict__ xm,
                                                float* __restrict__ z) {
    int tid = blockIdx.x * 256 + threadIdx.x;          // l*96 + e
    if (tid >= LL * 96) return;
    int e = tid % 96, l = tid / 96;
    const float4* xr = (const float4*)(x + l * CC);
    const float4* wr = (const float4*)(W + e * CC);
    float acc = 0.f;
#pragma unroll
    for (int c4 = 0; c4 < CC / 4; ++c4) {
        float4 a = xr[c4], b = wr[c4];
        acc += a.x * b.x + a.y * b.y + a.z * b.z + a.w * b.w;
    }
    if (e < DIN) xm[e * LL + l] = acc;
    else         z[l * DIN + (e - DIN)] = acc;
}

// ---- Kernel 2: depthwise 3x3x3 conv + bias + SiLU (natural layout only) ----
__global__ __launch_bounds__(256) void k_conv(const float* __restrict__ xm,
                                              const float* __restrict__ cw,
                                              const float* __restrict__ cb,
                                              float* __restrict__ xc) {
    int tid = blockIdx.x * 256 + threadIdx.x;          // d*LL + s
    if (tid >= DIN * LL) return;
    int s = tid & (LL - 1), d = tid >> 12;
    int dd = s & 15, w = (s >> 4) & 15, h = s >> 8;
    const float* wp = cw + d * 27;
    const float* xp = xm + d * LL;
    float acc = 0.f;
#pragma unroll
    for (int i = -1; i <= 1; ++i) {
        int hh = h + i; if (hh < 0 || hh > 15) continue;
#pragma unroll
        for (int j = -1; j <= 1; ++j) {
            int ww2 = w + j; if (ww2 < 0 || ww2 > 15) continue;
#pragma unroll
            for (int q = -1; q <= 1; ++q) {
                int dd2 = dd + q; if (dd2 < 0 || dd2 > 15) continue;
                acc += wp[(i + 1) * 9 + (j + 1) * 3 + (q + 1)]
                     * xp[hh * 256 + ww2 * 16 + dd2];
            }
        }
    }
    acc += cb[d];
    xc[tid] = acc / (1.f + __expf(-acc));              // SiLU
}

// ---- Kernel 3: permuted gather + x_proj + dt_proj + scan PHASE 1. ----------
// Block per (k, chunk), 768 thr = 48 d x 16 n. u gathered from xc via the
// direction permutation (once). Emits BC, packed ud=(u,delta), pa/hf.
__global__ __launch_bounds__(768) void k_xscan1(const float* __restrict__ xc,
                                                const float* __restrict__ xpw,
                                                const float* __restrict__ dtw,
                                                const float* __restrict__ dtb,
                                                const float* __restrict__ A_logs,
                                                float* __restrict__ BC,
                                                float* __restrict__ ud_g,
                                                float* __restrict__ pa_g,
                                                float* __restrict__ hf_g) {
    int k = blockIdx.x >> 6;
    int c = blockIdx.x & (NCH - 1);
    int l0 = c * CHL;
    int tid = threadIdx.x;
    __shared__ float xt[48 * 68];                      // u tile [d][64]
    __shared__ float xd[35 * 65];                      // x_dbl [c][64]
    __shared__ float2 ud[48 * 68];                     // (u, delta)
    int kperm = k & 3, krev = k & 4;
    // stage u tile via permuted gather from natural-layout xc
#pragma unroll
    for (int r = 0; r < 4; ++r) {
        int item = r * 768 + tid;                      // 3072 = 48 d * 64 i
        int d = item >> 6, i = item & 63;
        int lg = l0 + i;
        int ll = krev ? (LL - 1 - lg) : lg;
        int a = ll >> 8, b2 = (ll >> 4) & 15, c2 = ll & 15;
        int src;
        switch (kperm) {
            case 0: src = ll;                       break;
            case 1: src = b2 * 256 + a * 16 + c2;   break;
            case 2: src = c2 * 256 + b2 * 16 + a;   break;
            default: src = a * 256 + c2 * 16 + b2;  break;
        }
        xt[d * 68 + i] = xc[d * LL + src];
    }
    __syncthreads();
    // GEMM: x_dbl[c][l] = sum_d u[d][l] * xpw[k][c][d]
    if (tid < 560) {
        int cc = tid % 35, l4 = tid / 35;
        const float* wr = xpw + (k * 35 + cc) * DIN;   // L1-broadcast
        float4 acc = {0.f, 0.f, 0.f, 0.f};
#pragma unroll
        for (int d2 = 0; d2 < 48; ++d2) {
            float4 v = ((const float4*)(xt + d2 * 68))[l4];
            float w = wr[d2];
            acc.x += v.x * w; acc.y += v.y * w; acc.z += v.z * w; acc.w += v.w * w;
        }
        float* o = xd + cc * 65 + l4 * 4;
        o[0] = acc.x; o[1] = acc.y; o[2] = acc.z; o[3] = acc.w;
    }
    __syncthreads();
    // BC write (float4 over 32 cols)
    if (tid < 512) {
        int l = tid >> 3, q = tid & 7;
        float4 v;
#pragma unroll
        for (int j = 0; j < 4; ++j) (&v.x)[j] = xd[(3 + q * 4 + j) * 65 + l];
        ((float4*)(BC + ((size_t)(k * LL + l0 + l)) * 32))[q] = v;
    }
    // delta = softplus(dts @ dtw + bias); pack (u,delta) to LDS + global
#pragma unroll
    for (int r = 0; r < 4; ++r) {
        int item = r * 768 + tid;
        int d2 = item >> 6, l = item & 63;
        int gd = k * DIN + d2;
        float v = xd[l] * dtw[gd * 3] + xd[65 + l] * dtw[gd * 3 + 1]
                + xd[130 + l] * dtw[gd * 3 + 2] + dtb[gd];
        float sp = (v > 20.f) ? v : log1pf(__expf(v));
        float u = xt[d2 * 68 + l];
        float2 p = make_float2(u, sp);
        ud[d2 * 68 + l] = p;
        ((float2*)ud_g)[(size_t)gd * LL + l0 + l] = p;
    }
    __syncthreads();
    // scan phase 1: local chunk scan (h starts at 0)
    int d = tid >> 4, n = tid & 15;
    int gid = k * DIN + d;
    float A = -__expf(A_logs[gid * NN + n]);
    float h = 0.f, pa = 1.f;
#pragma unroll 8
    for (int i = 0; i < CHL; ++i) {
        float2 uv = ud[d * 68 + i];
        float Bv = xd[(3 + n) * 65 + i];
        float dA = __expf(uv.y * A);
        h = h * dA + uv.y * uv.x * Bv;
        pa *= dA;
    }
    size_t si = (size_t)gid * (NCH * 16) + c * 16 + n;
    pa_g[si] = pa;
    hf_g[si] = h;
}

// ---- Kernel 4: scan PHASE 2 — serial combine over 64 chunk summaries. ------
__global__ __launch_bounds__(256) void k_scan2(const float* __restrict__ pa_g,
                                               const float* __restrict__ hf_g,
                                               float* __restrict__ h0_g) {
    int t = blockIdx.x * 256 + threadIdx.x;            // gid*16 + n
    if (t >= KD * NN) return;
    int n = t & 15;
    int gid = t >> 4;
    size_t base = (size_t)gid * (NCH * 16) + n;
    float h = 0.f;
#pragma unroll 4
    for (int c = 0; c < NCH; ++c) {
        size_t idx = base + (size_t)c * 16;
        h0_g[idx] = h;
        h = h * pa_g[idx] + hf_g[idx];
    }
}

// ---- Kernel 5: scan PHASE 3 — re-scan seeded; DPP reduce; y2 store. --------
// Direct global reads (broadcast within n-groups), zero staging barriers.
__global__ __launch_bounds__(768) void k_scan3(const float* __restrict__ ud_g,
                                               const float* __restrict__ BC,
                                               const float* __restrict__ A_logs,
                                               const float* __restrict__ Ds,
                                               const float* __restrict__ h0_g,
                                               float* __restrict__ y2) {
    int k = blockIdx.x >> 6;
    int c = blockIdx.x & (NCH - 1);
    int l0 = c * CHL;
    int tid = threadIdx.x;
    int d = tid >> 4, n = tid & 15;
    int gid = k * DIN + d;
    __shared__ float y_t[48 * 68];
    float A = -__expf(A_logs[gid * NN + n]);
    float Dv = Ds[gid];
    float h = h0_g[(size_t)gid * (NCH * 16) + c * 16 + n];
    const float2* up = ((const float2*)ud_g) + (size_t)gid * LL + l0;
    const float* bp = BC + ((size_t)(k * LL + l0)) * 32 + n;
    const float* cp = bp + 16;
#pragma unroll 8
    for (int i = 0; i < CHL; ++i) {
        float2 uv = up[i];
        float Bv = bp[(size_t)i * 32];
        float Cv = cp[(size_t)i * 32];
        float dA = __expf(uv.y * A);
        h = h * dA + uv.y * uv.x * Bv;
        float p = row16_sum(h * Cv);                   // pure-VALU 16-lane sum
        if (n == 0) y_t[d * 68 + i] = p + Dv * uv.x;
    }
    __syncthreads();
    // de-permuted store: y2[s][k*48..+47], 192B contiguous per (l)
    {
        int g = tid >> 6, l = tid & 63;                // g: 0..11
        int lg = l0 + l;
        int ll = (k & 4) ? (LL - 1 - lg) : lg;
        int a = ll >> 8, b2 = (ll >> 4) & 15, c2 = ll & 15;
        int s;
        switch (k & 3) {
            case 0: s = ll;                        break;
            case 1: s = b2 * 256 + a * 16 + c2;    break;
            case 2: s = c2 * 256 + b2 * 16 + a;    break;
            default: s = a * 256 + c2 * 16 + b2;   break;
        }
        float4 v;
#pragma unroll
        for (int j = 0; j < 4; ++j) (&v.x)[j] = y_t[(g * 4 + j) * 68 + l];
        ((float4*)(y2 + (size_t)s * KD + k * DIN))[g] = v;
    }
}

// ---- Kernel 6: sum dirs + LayerNorm + gate + out_proj. Wave per s. ---------
__global__ __launch_bounds__(256) void k_final2(const float* __restrict__ y2,
                                                const float* __restrict__ z,
                                                const float* __restrict__ nw,
                                                const float* __restrict__ nb,
                                                const float* __restrict__ opw,
                                                float* __restrict__ out) {
    int wv = threadIdx.x >> 6, lane = threadIdx.x & 63;
    int s = blockIdx.x * 4 + wv;
    __shared__ float g[4][DIN];
    float val = 0.f;
    if (lane < DIN) {
        const float* yp = y2 + (size_t)s * KD + lane;
#pragma unroll
        for (int k = 0; k < KK; ++k) val += yp[k * DIN];
    }
    float m = val;
#pragma unroll
    for (int o = 32; o >= 1; o >>= 1) m += __shfl_xor(m, o, 64);
    m *= (1.f / 48.f);
    float dv = (lane < DIN) ? (val - m) : 0.f;
    float v2 = dv * dv;
#pragma unroll
    for (int o = 32; o >= 1; o >>= 1) v2 += __shfl_xor(v2, o, 64);
    v2 *= (1.f / 48.f);
    float inv = rsqrtf(v2 + 1e-5f);
    if (lane < DIN) {
        float yn = dv * inv * nw[lane] + nb[lane];
        float zz = z[s * DIN + lane];
        g[wv][lane] = yn * (zz / (1.f + __expf(-zz)));
    }
    __syncthreads();
    if (lane < DIN) {
        const float* wr = opw + lane * DIN;            // out_proj_w[c, e]
        float acc = 0.f;
#pragma unroll
        for (int e = 0; e < DIN; ++e) acc += g[wv][e] * wr[e];
        out[s * CC + lane] = acc;
    }
}

extern "C" void kernel_launch(void* const* d_in, const int* in_sizes, int n_in,
                              void* d_out, int out_size, void* d_ws, size_t ws_size,
                              hipStream_t stream) {
    const float* x      = (const float*)d_in[0];
    const float* ipw    = (const float*)d_in[1];
    const float* cw     = (const float*)d_in[2];
    const float* cb     = (const float*)d_in[3];
    const float* xpw    = (const float*)d_in[4];
    const float* dtw    = (const float*)d_in[5];
    const float* dtb    = (const float*)d_in[6];
    const float* A_logs = (const float*)d_in[7];
    const float* Ds     = (const float*)d_in[8];
    const float* nw     = (const float*)d_in[9];
    const float* nb     = (const float*)d_in[10];
    const float* opw    = (const float*)d_in[11];
    float* out = (float*)d_out;

    float* ws   = (float*)d_ws;
    float* xm   = ws;                                  // DIN*LL
    float* z    = xm + DIN * LL;                       // LL*DIN
    float* xc   = z + LL * DIN;                        // DIN*LL
    float* ud_g = xc + DIN * LL;                       // 2*KD*LL (float2)
    float* BC   = ud_g + (size_t)2 * KD * LL;          // KK*LL*32
    float* y2   = BC + (size_t)KK * LL * 32;           // LL*KD (s-major)
    float* pa_g = y2 + (size_t)LL * KD;                // KD*NCH*16
    float* hf_g = pa_g + (size_t)KD * NCH * 16;
    float* h0_g = hf_g + (size_t)KD * NCH * 16;

    k_inproj<<<(LL * 96 + 255) / 256, 256, 0, stream>>>(x, ipw, xm, z);
    k_conv<<<(DIN * LL + 255) / 256, 256, 0, stream>>>(xm, cw, cb, xc);
    k_xscan1<<<KK * NCH, 768, 0, stream>>>(xc, xpw, dtw, dtb, A_logs,
                                           BC, ud_g, pa_g, hf_g);
    k_scan2<<<(KD * NN + 255) / 256, 256, 0, stream>>>(pa_g, hf_g, h0_g);
    k_scan3<<<KK * NCH, 768, 0, stream>>>(ud_g, BC, A_logs, Ds, h0_g, y2);
    k_final2<<<LL / 4, 256, 0, stream>>>(y2, z, nw, nb, opw, out);
}